// Round 11
// baseline (2802.831 us; speedup 1.0000x reference)
//
#include <hip/hip_runtime.h>
#include <hip/hip_bf16.h>

#define S 4096
#define E 256
#define HH 256
#define TT 16
#define NEG_ -10000.0f
#define START_ 14
#define STOP_ 15
// hs layout: per direction [256-float slack row][S*256 data]
#define DSTRIDE_F (S * 256 + 256)

// ---------- fast math helpers (host-side kernels) ----------
__device__ __forceinline__ float fast_exp(float x) {           // e^x
    return __builtin_amdgcn_exp2f(x * 1.4426950408889634f);
}
__device__ __forceinline__ float fast_log(float x) {           // ln
    return 0.6931471805599453f * __builtin_amdgcn_logf(x);
}

// ---------- K0: quantize W_hh to int4 (per-row scale m/7); h0 FIXED 1/7 ----------
__global__ __launch_bounds__(64) void quant4_kernel(
    const float* __restrict__ Wf, const float* __restrict__ Wb,
    const float* __restrict__ h0,
    int* __restrict__ wq4, float* __restrict__ wscale,
    int* __restrict__ hq0p)
{
    int blk = blockIdx.x, lane = threadIdx.x;
    const float* src;
    int* dst;
    float* scl = nullptr;
    bool fixed = false;
    if (blk < 2048) {
        int d = blk >> 10, r = blk & 1023;
        src = (d == 0 ? Wf : Wb) + (size_t)r * 256;
        dst = wq4 + ((size_t)(d * 1024 + r)) * 32;
        scl = wscale + (d * 1024 + r);
    } else {
        int d = blk - 2048;
        src = h0 + (size_t)d * 256;
        dst = hq0p + d * 32;
        fixed = true;   // h0 quantized at steady-state scale 1/7 (clamped)
    }
    float4 a = make_float4(0.f, 0.f, 0.f, 0.f), b = a;
    if (lane < 32) {
        a = ((const float4*)src)[2 * lane];
        b = ((const float4*)src)[2 * lane + 1];
    }
    float f[8] = {a.x, a.y, a.z, a.w, b.x, b.y, b.z, b.w};
    float m = 0.f;
    #pragma unroll
    for (int k = 0; k < 8; ++k) m = fmaxf(m, fabsf(f[k]));
    #pragma unroll
    for (int off = 1; off < 64; off <<= 1) m = fmaxf(m, __shfl_xor(m, off, 64));
    m = fmaxf(m, 1e-20f);
    float inv = fixed ? 7.0f : (7.0f / m);
    if (lane < 32) {
        int dw = 0;
        #pragma unroll
        for (int k = 0; k < 8; ++k) {
            int q = __float2int_rn(f[k] * inv);
            q = max(-8, min(7, q));
            dw |= (q & 0xF) << (4 * k);
        }
        dst[lane] = dw;
    }
    if (!fixed && lane == 0) *scl = m / 7.0f;
}

// ---------- K0b: transpose W_ih -> WT[dir][e][r] for coalesced xg reads ----------
__global__ __launch_bounds__(256) void transpose_kernel(
    const float* __restrict__ Wf, const float* __restrict__ Wb,
    float* __restrict__ WT)
{
    __shared__ float tile[32][33];
    const int dir = blockIdx.z;
    const float* W = dir ? Wb : Wf;
    const int r0 = blockIdx.x * 32, e0 = blockIdx.y * 32;
    const int tr = threadIdx.x & 31, tc = threadIdx.x >> 5;   // 32 x 8
    #pragma unroll
    for (int i = 0; i < 32; i += 8)
        tile[tc + i][tr] = W[(size_t)(r0 + tc + i) * 256 + e0 + tr];
    __syncthreads();
    float* out = WT + (size_t)dir * 256 * 1024;
    #pragma unroll
    for (int i = 0; i < 32; i += 8)
        out[(size_t)(e0 + tc + i) * 1024 + r0 + tr] = tile[tr][tc + i];
}

// ---------- K1: xg (coalesced via WT), stored float4 {i,f,g,o} per cell ----------
__global__ __launch_bounds__(256) void xg_kernel(
    const int* __restrict__ sent, const float* __restrict__ embed,
    const float* __restrict__ WT,
    const float* __restrict__ bihf, const float* __restrict__ bhhf,
    const float* __restrict__ bihb, const float* __restrict__ bhhb,
    float* __restrict__ xg)
{
    const int dir = blockIdx.y;
    const int t0 = blockIdx.x * 16;
    const int tid = threadIdx.x;
    const float* Wt = WT + (size_t)dir * 256 * 1024;
    __shared__ float xt[16][256];
    for (int tt = 0; tt < 16; ++tt) {
        int t = t0 + tt;
        int pos = dir ? (S - 1 - t) : t;
        int w = sent[pos];
        xt[tt][tid] = embed[(size_t)w * 256 + tid];
    }
    __syncthreads();
    float acc[4][16];
    #pragma unroll
    for (int rc = 0; rc < 4; ++rc)
        #pragma unroll
        for (int tt = 0; tt < 16; ++tt) acc[rc][tt] = 0.f;
    for (int e = 0; e < 256; ++e) {
        float xv[16];
        #pragma unroll
        for (int tt = 0; tt < 16; ++tt) xv[tt] = xt[tt][e];
        const float* wrow = Wt + (size_t)e * 1024;
        #pragma unroll
        for (int rc = 0; rc < 4; ++rc) {
            float w = wrow[rc * 256 + tid];        // consecutive tid -> coalesced
            #pragma unroll
            for (int tt = 0; tt < 16; ++tt) acc[rc][tt] += w * xv[tt];
        }
    }
    const float* bih = dir ? bihb : bihf;
    const float* bhh = dir ? bhhb : bhhf;
    float b0 = bih[0 * 256 + tid] + bhh[0 * 256 + tid];
    float b1 = bih[1 * 256 + tid] + bhh[1 * 256 + tid];
    float b2 = bih[2 * 256 + tid] + bhh[2 * 256 + tid];
    float b3 = bih[3 * 256 + tid] + bhh[3 * 256 + tid];
    #pragma unroll
    for (int tt = 0; tt < 16; ++tt) {
        float4 v;
        v.x = acc[0][tt] + b0;
        v.y = acc[1][tt] + b1;
        v.z = acc[2][tt] + b2;
        v.w = acc[3][tt] + b3;
        ((float4*)(xg + ((size_t)dir * S + (t0 + tt)) * 1024))[tid] = v;
    }
}

// ---------- K2: LSTM, K-SPLIT: 512 thr, 2 waves/SIMD ----------
// Thread t: cell m=t&255, K-half kh=t>>8 (elements [kh*128, kh*128+128)).
// Per thread: 4 gate-rows x 16 int4-dwords = 64 weight VGPRs, 64 dot8.
// Partial sums exchanged via LDS b128 (barrier1); BOTH halves compute the
// tail redundantly (identical fp math); kh=0 quad leaders write packed h.
// LDS map: hbuf0 @0 (128B), hbuf1 @128, partials(kh0) @1024, partials(kh1)
// @5120, dump @9216. Regs: W i/f/g/o v32-47/48-63/64-79/80-95; h v96-111;
// acc v112-115; xgA v116-119, xgB v120-123; addrs v124-129; partner
// v130-133; temps v134-145; c v146; lag-h v147; shift v148.
#define D8(a,w,h) "v_dot8_i32_i4 " a ", " w ", " h ", " a "\n\t"
#define CHK(H0,H1,H2,H3, I0,I1,I2,I3, F0,F1,F2,F3, G0,G1,G2,G3, O0,O1,O2,O3) \
 D8("v112",I0,H0) D8("v113",F0,H0) D8("v114",G0,H0) D8("v115",O0,H0) \
 D8("v112",I1,H1) D8("v113",F1,H1) D8("v114",G1,H1) D8("v115",O1,H1) \
 D8("v112",I2,H2) D8("v113",F2,H2) D8("v114",G2,H2) D8("v115",O2,H2) \
 D8("v112",I3,H3) D8("v113",F3,H3) D8("v114",G3,H3) D8("v115",O3,H3)

#define LSTM_BODY(XI, XF, XG, XO, NQUAD) \
  "ds_read_b128 v[96:99],   v126\n\t" \
  "ds_read_b128 v[100:103], v126 offset:16\n\t" \
  "ds_read_b128 v[104:107], v126 offset:32\n\t" \
  "ds_read_b128 v[108:111], v126 offset:48\n\t" \
  "v_xor_b32 v126, 0x80, v126\n\t" \
  "global_store_dword v125, v147, %[shs]\n\t" \
  "v_add_u32 v125, 0x400, v125\n\t" \
  "global_load_dwordx4 " NQUAD ", v124, %[sxg]\n\t" \
  "v_add_u32 v124, 0x1000, v124\n\t" \
  "s_waitcnt lgkmcnt(3)\n\t" \
  CHK("v96","v97","v98","v99", "v32","v33","v34","v35", "v48","v49","v50","v51", "v64","v65","v66","v67", "v80","v81","v82","v83") \
  "s_waitcnt lgkmcnt(2)\n\t" \
  CHK("v100","v101","v102","v103", "v36","v37","v38","v39", "v52","v53","v54","v55", "v68","v69","v70","v71", "v84","v85","v86","v87") \
  "s_waitcnt lgkmcnt(1)\n\t" \
  CHK("v104","v105","v106","v107", "v40","v41","v42","v43", "v56","v57","v58","v59", "v72","v73","v74","v75", "v88","v89","v90","v91") \
  "s_waitcnt lgkmcnt(0)\n\t" \
  CHK("v108","v109","v110","v111", "v44","v45","v46","v47", "v60","v61","v62","v63", "v76","v77","v78","v79", "v92","v93","v94","v95") \
  "ds_write_b128 v128, v[112:115]\n\t" \
  "s_waitcnt lgkmcnt(0)\n\t" \
  "s_barrier\n\t" \
  "ds_read_b128 v[130:133], v129\n\t" \
  "s_waitcnt lgkmcnt(0)\n\t" \
  "v_add_u32 v112, v112, v130\n\t" \
  "v_add_u32 v113, v113, v131\n\t" \
  "v_add_u32 v114, v114, v132\n\t" \
  "v_add_u32 v115, v115, v133\n\t" \
  "v_cvt_f32_i32 v134, v112\n\t" \
  "v_cvt_f32_i32 v135, v113\n\t" \
  "v_cvt_f32_i32 v136, v114\n\t" \
  "v_cvt_f32_i32 v137, v115\n\t" \
  "s_waitcnt vmcnt(2)\n\t" \
  "v_fma_f32 v138, %[sci], v134, " XI "\n\t" \
  "v_fma_f32 v139, %[scf], v135, " XF "\n\t" \
  "v_fma_f32 v140, %[scg], v136, " XG "\n\t" \
  "v_fma_f32 v141, %[sco], v137, " XO "\n\t" \
  "v_mul_f32 v134, %[nk], v138\n\t" \
  "v_mul_f32 v135, %[nk], v139\n\t" \
  "v_mul_f32 v137, %[nk], v141\n\t" \
  "v_med3_f32 v140, v140, %[ncl], %[pcl]\n\t" \
  "v_mul_f32 v136, %[k2], v140\n\t" \
  "v_exp_f32 v134, v134\n\t" \
  "v_exp_f32 v135, v135\n\t" \
  "v_exp_f32 v137, v137\n\t" \
  "v_exp_f32 v136, v136\n\t" \
  "s_nop 1\n\t" \
  "v_add_f32 v138, 1.0, v134\n\t" \
  "v_add_f32 v139, 1.0, v135\n\t" \
  "v_add_f32 v141, 1.0, v137\n\t" \
  "v_add_f32 v142, 1.0, v136\n\t" \
  "v_add_f32 v143, -1.0, v136\n\t" \
  "v_rcp_f32 v138, v138\n\t" \
  "v_rcp_f32 v139, v139\n\t" \
  "v_rcp_f32 v141, v141\n\t" \
  "v_rcp_f32 v142, v142\n\t" \
  "s_nop 1\n\t" \
  "v_mul_f32 v143, v143, v142\n\t" \
  "v_mul_f32 v144, %[c7], v141\n\t" \
  "v_mul_f32 v146, v139, v146\n\t" \
  "v_fmac_f32 v146, v138, v143\n\t" \
  "v_med3_f32 v134, v146, %[ncl], %[pcl]\n\t" \
  "v_mul_f32 v134, %[k2], v134\n\t" \
  "v_exp_f32 v134, v134\n\t" \
  "s_nop 1\n\t" \
  "v_add_f32 v135, -1.0, v134\n\t" \
  "v_add_f32 v136, 1.0, v134\n\t" \
  "v_rcp_f32 v136, v136\n\t" \
  "s_nop 1\n\t" \
  "v_mul_f32 v135, v135, v136\n\t" \
  "v_mul_f32 v143, v144, v135\n\t" \
  "v_add_f32 v134, 0x4b400000, v143\n\t" \
  "v_and_b32 v134, 15, v134\n\t" \
  "v_lshlrev_b32 v134, v148, v134\n\t" \
  "v_mul_f32 v147, %[i7], v143\n\t" \
  "s_nop 1\n\t" \
  "v_mov_b32_dpp v135, v134 quad_perm:[1,0,3,2] row_mask:0xf bank_mask:0xf\n\t" \
  "v_or_b32 v134, v134, v135\n\t" \
  "s_nop 1\n\t" \
  "v_mov_b32_dpp v135, v134 quad_perm:[2,3,0,1] row_mask:0xf bank_mask:0xf\n\t" \
  "v_or_b32 v134, v134, v135\n\t" \
  "ds_write_b16 v127, v134\n\t" \
  "v_xor_b32 v127, 0x80, v127\n\t" \
  "v_mov_b32 v112, 0\n\t" \
  "v_mov_b32 v113, 0\n\t" \
  "v_mov_b32 v114, 0\n\t" \
  "v_mov_b32 v115, 0\n\t" \
  "s_waitcnt lgkmcnt(0)\n\t" \
  "s_barrier\n\t"

__global__ __launch_bounds__(512, 2) void lstm_kernel(
    const float* __restrict__ xg, const int* __restrict__ wq4,
    const float* __restrict__ wscale, const int* __restrict__ hq0p,
    const float* __restrict__ c0, float* __restrict__ hs)
{
    const int d = blockIdx.x;
    const int t = threadIdx.x;
    const int m = t & 255;       // cell
    const int kh = t >> 8;       // K-half

    __shared__ alignas(16) int hq4buf[2432];   // 9728 B (map in header comment)

    const int*   wq_d = wq4 + (size_t)d * 32768;
    const float* xg_d = xg + (size_t)d * S * 1024;
    float*       hs_d = hs + (size_t)d * DSTRIDE_F;   // slack row first
    const float sci = wscale[d * 1024 + m]       * (1.0f / 7.0f);
    const float scf = wscale[d * 1024 + 256 + m] * (1.0f / 7.0f);
    const float scg = wscale[d * 1024 + 512 + m] * (1.0f / 7.0f);
    const float sco = wscale[d * 1024 + 768 + m] * (1.0f / 7.0f);
    const float c0v = c0[d * 256 + m];
    const int h0v = hq0p[d * 32 + (t & 31)];
    const unsigned dmp = 9216u + (unsigned)(t & 127) * 4u;
    const unsigned h0a = (t < 32) ? (unsigned)t * 4u : dmp;
    const unsigned xai = (unsigned)m * 16u;
    const unsigned hsi = (unsigned)m * 4u;      // first (lagged) store -> slack row
    const unsigned hra = (unsigned)kh * 64u;    // h read: own half of hbuf0
    const unsigned hwa = (kh == 0 && (t & 3) == 0) ? (128u + (unsigned)(m >> 1)) : dmp;
    const unsigned pwa = 1024u + (unsigned)kh * 4096u + (unsigned)m * 16u;
    const unsigned pra = 1024u + (unsigned)(kh ^ 1) * 4096u + (unsigned)m * 16u;
    const unsigned voW = (unsigned)m * 128u + (unsigned)kh * 64u;  // +0x8000/gate
    const unsigned shf = (unsigned)(t & 3) * 4u;
    const float nk = -1.4426950408889634f;
    const float k2 = 2.8853900817779268f;
    const float c7 = 7.0f;
    const float i7 = 1.0f / 7.0f;
    const float ncl = -30.0f, pcl = 30.0f;
    const unsigned lds_keep = (unsigned)(size_t)&hq4buf[0];
    int cnt = S / 2;   // body unrolled x2

    asm volatile(
        // ---- prologue ----
        "v_mov_b32 v124, %[xai]\n\t"
        "v_mov_b32 v125, %[hsi]\n\t"
        "v_mov_b32 v126, %[hra]\n\t"
        "v_mov_b32 v127, %[hwa]\n\t"
        "v_mov_b32 v128, %[pwa]\n\t"
        "v_mov_b32 v129, %[pra]\n\t"
        "v_mov_b32 v146, %[c0v]\n\t"
        "v_mov_b32 v147, 0\n\t"
        "v_mov_b32 v148, %[shf]\n\t"
        "v_mov_b32 v112, 0\n\t"
        "v_mov_b32 v113, 0\n\t"
        "v_mov_b32 v114, 0\n\t"
        "v_mov_b32 v115, 0\n\t"
        "ds_write_b32 %[h0a], %[h0v]\n\t"
        "v_mov_b32 v134, %[voW]\n\t"
        "global_load_dwordx4 v[32:35], v134, %[swq]\n\t"
        "global_load_dwordx4 v[36:39], v134, %[swq] offset:16\n\t"
        "global_load_dwordx4 v[40:43], v134, %[swq] offset:32\n\t"
        "global_load_dwordx4 v[44:47], v134, %[swq] offset:48\n\t"
        "v_add_u32 v134, 0x8000, v134\n\t"
        "global_load_dwordx4 v[48:51], v134, %[swq]\n\t"
        "global_load_dwordx4 v[52:55], v134, %[swq] offset:16\n\t"
        "global_load_dwordx4 v[56:59], v134, %[swq] offset:32\n\t"
        "global_load_dwordx4 v[60:63], v134, %[swq] offset:48\n\t"
        "v_add_u32 v134, 0x8000, v134\n\t"
        "global_load_dwordx4 v[64:67], v134, %[swq]\n\t"
        "global_load_dwordx4 v[68:71], v134, %[swq] offset:16\n\t"
        "global_load_dwordx4 v[72:75], v134, %[swq] offset:32\n\t"
        "global_load_dwordx4 v[76:79], v134, %[swq] offset:48\n\t"
        "v_add_u32 v134, 0x8000, v134\n\t"
        "global_load_dwordx4 v[80:83], v134, %[swq]\n\t"
        "global_load_dwordx4 v[84:87], v134, %[swq] offset:16\n\t"
        "global_load_dwordx4 v[88:91], v134, %[swq] offset:32\n\t"
        "global_load_dwordx4 v[92:95], v134, %[swq] offset:48\n\t"
        "global_load_dwordx4 v[116:119], v124, %[sxg]\n\t"
        "v_add_u32 v124, 0x1000, v124\n\t"
        "s_waitcnt vmcnt(0) lgkmcnt(0)\n\t"
        "s_barrier\n\t"
        // ---- main loop: 2 steps per iteration (depth-1 xg rotation) ----
        "Llstm%=:\n\t"
        LSTM_BODY("v116", "v117", "v118", "v119", "v[120:123]")
        LSTM_BODY("v120", "v121", "v122", "v123", "v[116:119]")
        "s_add_i32 %[cnt], %[cnt], -1\n\t"
        "s_cmp_lg_u32 %[cnt], 0\n\t"
        "s_cbranch_scc1 Llstm%=\n\t"
        // ---- epilogue: store last h ----
        "global_store_dword v125, v147, %[shs]\n\t"
        : [cnt] "+s"(cnt)
        : [sxg] "s"(xg_d), [shs] "s"(hs_d), [swq] "s"(wq_d),
          [xai] "v"(xai), [hsi] "v"(hsi), [hra] "v"(hra), [hwa] "v"(hwa),
          [pwa] "v"(pwa), [pra] "v"(pra),
          [c0v] "v"(c0v), [h0a] "v"(h0a), [h0v] "v"(h0v),
          [sci] "v"(sci), [scf] "v"(scf), [scg] "v"(scg), [sco] "v"(sco),
          [nk] "v"(nk), [k2] "v"(k2), [c7] "v"(c7), [i7] "v"(i7),
          [ncl] "v"(ncl), [pcl] "v"(pcl),
          [voW] "v"(voW), [shf] "v"(shf), [keep] "v"(lds_keep)
        : "memory", "scc",
          "v32","v33","v34","v35","v36","v37","v38","v39",
          "v40","v41","v42","v43","v44","v45","v46","v47",
          "v48","v49","v50","v51","v52","v53","v54","v55",
          "v56","v57","v58","v59","v60","v61","v62","v63",
          "v64","v65","v66","v67","v68","v69","v70","v71",
          "v72","v73","v74","v75","v76","v77","v78","v79",
          "v80","v81","v82","v83","v84","v85","v86","v87",
          "v88","v89","v90","v91","v92","v93","v94","v95",
          "v96","v97","v98","v99","v100","v101","v102","v103",
          "v104","v105","v106","v107","v108","v109","v110","v111",
          "v112","v113","v114","v115","v116","v117","v118","v119",
          "v120","v121","v122","v123","v124","v125","v126","v127",
          "v128","v129","v130","v131","v132","v133","v134","v135",
          "v136","v137","v138","v139","v140","v141","v142","v143",
          "v144","v145","v146","v147","v148");
}

// ---------- K3: feats[t][tag] = b_out[tag] + W_out[tag] . [hf[t], hb[t]] ----------
__global__ __launch_bounds__(256) void feats_kernel(
    const float* __restrict__ hsf, const float* __restrict__ hsb,
    const float* __restrict__ Wout,
    const float* __restrict__ bout, float* __restrict__ feats)
{
    __shared__ float Wl[16][513];
    int tid = threadIdx.x;
    for (int i = tid; i < 16 * 512; i += 256) Wl[i >> 9][i & 511] = Wout[i];
    __syncthreads();
    int tt = tid >> 4, tag = tid & 15;
    int tcur = blockIdx.x * 16 + tt;
    const float* hf = hsf + (size_t)tcur * 256;
    const float* hb = hsb + (size_t)(S - 1 - tcur) * 256;
    float acc = bout[tag];
    for (int k = 0; k < 256; ++k) acc += Wl[tag][k] * hf[k];
    for (int k = 0; k < 256; ++k) acc += Wl[tag][256 + k] * hb[k];
    feats[(size_t)tcur * 16 + tag] = acc;
}

// ---------- K4a: CRF chunk products in log semiring ----------
__global__ __launch_bounds__(256) void crf_chunk_kernel(
    const float* __restrict__ feats, const float* __restrict__ trans,
    float* __restrict__ P)
{
    int chunk = blockIdx.x;
    int tid = threadIdx.x;
    int i = tid >> 4, jj = tid & 15;
    __shared__ float Mt[2][16][17];   // Mt[buf][j][k] = M[k][j]
    float tr[16];
    #pragma unroll
    for (int k = 0; k < 16; ++k) tr[k] = trans[i * 16 + k];
    int t0 = chunk * 64;
    float emit = feats[(size_t)t0 * 16 + i];
    Mt[0][jj][i] = tr[jj] + emit;     // init M = A_{t0}
    __syncthreads();
    int cur = 0;
    float em_next = feats[(size_t)(t0 + 1) * 16 + i];
    for (int s = 1; s < 64; ++s) {
        float em = em_next;
        if (s + 1 < 64) em_next = feats[(size_t)(t0 + s + 1) * 16 + i];
        float v[16];
        #pragma unroll
        for (int k = 0; k < 16; ++k) v[k] = tr[k] + Mt[cur][jj][k];
        float m = v[0];
        #pragma unroll
        for (int k = 1; k < 16; ++k) m = fmaxf(m, v[k]);
        float ssum = 0.f;
        #pragma unroll
        for (int k = 0; k < 16; ++k) ssum += fast_exp(v[k] - m);
        float nv = em + m + fast_log(ssum);
        Mt[cur ^ 1][jj][i] = nv;
        cur ^= 1;
        __syncthreads();
    }
    P[((size_t)chunk * 16 + i) * 16 + jj] = Mt[cur][jj][i];
}

// ---------- K4b: fold 64 chunk matrices through alpha ----------
__global__ __launch_bounds__(256) void crf_fold_kernel(
    const float* __restrict__ P, const float* __restrict__ trans,
    float* __restrict__ out)
{
    int tid = threadIdx.x;
    int i = tid >> 4, jj = tid & 15;
    __shared__ float alpha[16];
    if (tid < 16) alpha[tid] = (tid == START_) ? 0.0f : NEG_;
    __syncthreads();
    for (int cc = 0; cc < 64; ++cc) {
        float pv = P[((size_t)cc * 16 + i) * 16 + jj];
        float v = pv + alpha[jj];
        float m = v;
        #pragma unroll
        for (int off = 1; off < 16; off <<= 1) m = fmaxf(m, __shfl_xor(m, off, 64));
        float e = fast_exp(v - m);
        #pragma unroll
        for (int off = 1; off < 16; off <<= 1) e += __shfl_xor(e, off, 64);
        float nv = m + fast_log(e);
        __syncthreads();
        if (jj == 0) alpha[i] = nv;
        __syncthreads();
    }
    if (tid < 16) {
        float v = alpha[tid] + trans[STOP_ * 16 + tid];
        float m = v;
        #pragma unroll
        for (int off = 1; off < 16; off <<= 1) m = fmaxf(m, __shfl_xor(m, off, 64));
        float e = fast_exp(v - m);
        #pragma unroll
        for (int off = 1; off < 16; off <<= 1) e += __shfl_xor(e, off, 64);
        if (tid == 0) out[0] = m + fast_log(e);
    }
}

extern "C" void kernel_launch(void* const* d_in, const int* in_sizes, int n_in,
                              void* d_out, int out_size, void* d_ws, size_t ws_size,
                              hipStream_t stream) {
    const int*   sent  = (const int*)d_in[0];
    const float* embed = (const float*)d_in[1];
    const float* Wihf  = (const float*)d_in[2];
    const float* Whhf  = (const float*)d_in[3];
    const float* bihf  = (const float*)d_in[4];
    const float* bhhf  = (const float*)d_in[5];
    const float* Wihb  = (const float*)d_in[6];
    const float* Whhb  = (const float*)d_in[7];
    const float* bihb  = (const float*)d_in[8];
    const float* bhhb  = (const float*)d_in[9];
    const float* Wout  = (const float*)d_in[10];
    const float* bout  = (const float*)d_in[11];
    const float* trans = (const float*)d_in[12];
    const float* h0    = (const float*)d_in[13];
    const float* c0    = (const float*)d_in[14];
    float* out = (float*)d_out;

    char* ws = (char*)d_ws;
    constexpr size_t OFF_XG     = 0;                                      // 32MB
    constexpr size_t OFF_WQ     = OFF_XG + (size_t)2 * S * 1024 * 4;      // 256KB (int4)
    constexpr size_t OFF_WSCALE = OFF_WQ + (size_t)2 * 1024 * 32 * 4;     // 8KB
    constexpr size_t OFF_HQ0    = OFF_WSCALE + 2 * 1024 * 4;              // 256B
    constexpr size_t OFF_WT     = OFF_HQ0 + 256;                          // 2MB
    constexpr size_t OFF_HS     = OFF_WT + (size_t)2 * 256 * 1024 * 4;    // 2*(4MB+1KB)
    constexpr size_t OFF_FEATS  = OFF_HS + (size_t)2 * DSTRIDE_F * 4;     // 256KB
    constexpr size_t OFF_P      = OFF_FEATS + (size_t)S * 16 * 4;         // 64KB

    float* xg     = (float*)(ws + OFF_XG);
    int*   wq4    = (int*)(ws + OFF_WQ);
    float* wscale = (float*)(ws + OFF_WSCALE);
    int*   hq0p   = (int*)(ws + OFF_HQ0);
    float* WT     = (float*)(ws + OFF_WT);
    float* hs     = (float*)(ws + OFF_HS);
    float* feats  = (float*)(ws + OFF_FEATS);
    float* P      = (float*)(ws + OFF_P);

    quant4_kernel<<<dim3(2050), dim3(64), 0, stream>>>(Whhf, Whhb, h0, wq4, wscale, hq0p);
    transpose_kernel<<<dim3(32, 8, 2), dim3(256), 0, stream>>>(Wihf, Wihb, WT);
    xg_kernel<<<dim3(256, 2), dim3(256), 0, stream>>>(sent, embed, WT, bihf, bhhf,
                                                      bihb, bhhb, xg);
    lstm_kernel<<<dim3(2), dim3(512), 0, stream>>>(xg, wq4, wscale, hq0p, c0, hs);
    feats_kernel<<<dim3(256), dim3(256), 0, stream>>>(hs + 256, hs + DSTRIDE_F + 256,
                                                      Wout, bout, feats);
    crf_chunk_kernel<<<dim3(64), dim3(256), 0, stream>>>(feats, trans, P);
    crf_fold_kernel<<<dim3(1), dim3(256), 0, stream>>>(P, trans, out);
}

// Round 12
// 2154.325 us; speedup vs baseline: 1.3010x; 1.3010x over previous
//
#include <hip/hip_runtime.h>
#include <hip/hip_bf16.h>

#define S 4096
#define E 256
#define HH 256
#define TT 16
#define NEG_ -10000.0f
#define START_ 14
#define STOP_ 15
// hs layout: per direction [256-float slack row][S*256 data]
#define DSTRIDE_F (S * 256 + 256)

// ---------- fast math helpers (host-side kernels) ----------
__device__ __forceinline__ float fast_exp(float x) {           // e^x
    return __builtin_amdgcn_exp2f(x * 1.4426950408889634f);
}
__device__ __forceinline__ float fast_log(float x) {           // ln
    return 0.6931471805599453f * __builtin_amdgcn_logf(x);
}

// ---------- K0: quantize W_hh to int4 (per-row scale m/7); h0 FIXED 1/7 ----------
__global__ __launch_bounds__(64) void quant4_kernel(
    const float* __restrict__ Wf, const float* __restrict__ Wb,
    const float* __restrict__ h0,
    int* __restrict__ wq4, float* __restrict__ wscale,
    int* __restrict__ hq0p)
{
    int blk = blockIdx.x, lane = threadIdx.x;
    const float* src;
    int* dst;
    float* scl = nullptr;
    bool fixed = false;
    if (blk < 2048) {
        int d = blk >> 10, r = blk & 1023;
        src = (d == 0 ? Wf : Wb) + (size_t)r * 256;
        dst = wq4 + ((size_t)(d * 1024 + r)) * 32;
        scl = wscale + (d * 1024 + r);
    } else {
        int d = blk - 2048;
        src = h0 + (size_t)d * 256;
        dst = hq0p + d * 32;
        fixed = true;   // h0 quantized at steady-state scale 1/7 (clamped)
    }
    float4 a = make_float4(0.f, 0.f, 0.f, 0.f), b = a;
    if (lane < 32) {
        a = ((const float4*)src)[2 * lane];
        b = ((const float4*)src)[2 * lane + 1];
    }
    float f[8] = {a.x, a.y, a.z, a.w, b.x, b.y, b.z, b.w};
    float m = 0.f;
    #pragma unroll
    for (int k = 0; k < 8; ++k) m = fmaxf(m, fabsf(f[k]));
    #pragma unroll
    for (int off = 1; off < 64; off <<= 1) m = fmaxf(m, __shfl_xor(m, off, 64));
    m = fmaxf(m, 1e-20f);
    float inv = fixed ? 7.0f : (7.0f / m);
    if (lane < 32) {
        int dw = 0;
        #pragma unroll
        for (int k = 0; k < 8; ++k) {
            int q = __float2int_rn(f[k] * inv);
            q = max(-8, min(7, q));
            dw |= (q & 0xF) << (4 * k);
        }
        dst[lane] = dw;
    }
    if (!fixed && lane == 0) *scl = m / 7.0f;
}

// ---------- K0b: transpose W_ih -> WT[dir][e][r] for coalesced xg reads ----------
__global__ __launch_bounds__(256) void transpose_kernel(
    const float* __restrict__ Wf, const float* __restrict__ Wb,
    float* __restrict__ WT)
{
    __shared__ float tile[32][33];
    const int dir = blockIdx.z;
    const float* W = dir ? Wb : Wf;
    const int r0 = blockIdx.x * 32, e0 = blockIdx.y * 32;
    const int tr = threadIdx.x & 31, tc = threadIdx.x >> 5;   // 32 x 8
    #pragma unroll
    for (int i = 0; i < 32; i += 8)
        tile[tc + i][tr] = W[(size_t)(r0 + tc + i) * 256 + e0 + tr];
    __syncthreads();
    float* out = WT + (size_t)dir * 256 * 1024;
    #pragma unroll
    for (int i = 0; i < 32; i += 8)
        out[(size_t)(e0 + tc + i) * 1024 + r0 + tr] = tile[tr][tc + i];
}

// ---------- K1: xg (coalesced via WT), stored float4 {i,f,g,o} per cell ----------
__global__ __launch_bounds__(256) void xg_kernel(
    const int* __restrict__ sent, const float* __restrict__ embed,
    const float* __restrict__ WT,
    const float* __restrict__ bihf, const float* __restrict__ bhhf,
    const float* __restrict__ bihb, const float* __restrict__ bhhb,
    float* __restrict__ xg)
{
    const int dir = blockIdx.y;
    const int t0 = blockIdx.x * 16;
    const int tid = threadIdx.x;
    const float* Wt = WT + (size_t)dir * 256 * 1024;
    __shared__ float xt[16][256];
    for (int tt = 0; tt < 16; ++tt) {
        int t = t0 + tt;
        int pos = dir ? (S - 1 - t) : t;
        int w = sent[pos];
        xt[tt][tid] = embed[(size_t)w * 256 + tid];
    }
    __syncthreads();
    float acc[4][16];
    #pragma unroll
    for (int rc = 0; rc < 4; ++rc)
        #pragma unroll
        for (int tt = 0; tt < 16; ++tt) acc[rc][tt] = 0.f;
    for (int e = 0; e < 256; ++e) {
        float xv[16];
        #pragma unroll
        for (int tt = 0; tt < 16; ++tt) xv[tt] = xt[tt][e];
        const float* wrow = Wt + (size_t)e * 1024;
        #pragma unroll
        for (int rc = 0; rc < 4; ++rc) {
            float w = wrow[rc * 256 + tid];        // consecutive tid -> coalesced
            #pragma unroll
            for (int tt = 0; tt < 16; ++tt) acc[rc][tt] += w * xv[tt];
        }
    }
    const float* bih = dir ? bihb : bihf;
    const float* bhh = dir ? bhhb : bhhf;
    float b0 = bih[0 * 256 + tid] + bhh[0 * 256 + tid];
    float b1 = bih[1 * 256 + tid] + bhh[1 * 256 + tid];
    float b2 = bih[2 * 256 + tid] + bhh[2 * 256 + tid];
    float b3 = bih[3 * 256 + tid] + bhh[3 * 256 + tid];
    #pragma unroll
    for (int tt = 0; tt < 16; ++tt) {
        float4 v;
        v.x = acc[0][tt] + b0;
        v.y = acc[1][tt] + b1;
        v.z = acc[2][tt] + b2;
        v.w = acc[3][tt] + b3;
        ((float4*)(xg + ((size_t)dir * S + (t0 + tt)) * 1024))[tid] = v;
    }
}

// ---------- K2: sequential LSTM, 256 threads, whole cell per thread ----------
// R10 configuration (best measured: lstm 1998us, 1171 cyc/step).
// Depth-1 xg pipeline: body k consumes quad loaded in body k-1, issues
// store(h_{k-1}) + load(k+1); vmcnt(2) retires the previous load.
#define D8(a,w,h) "v_dot8_i32_i4 " a ", " w ", " h ", " a "\n\t"
#define CH(H0,H1,H2,H3, I0,I1,I2,I3, F0,F1,F2,F3, G0,G1,G2,G3, O0,O1,O2,O3) \
 D8("v192",I0,H0) D8("v193",F0,H0) D8("v194",G0,H0) D8("v195",O0,H0) \
 D8("v192",I1,H1) D8("v193",F1,H1) D8("v194",G1,H1) D8("v195",O1,H1) \
 D8("v192",I2,H2) D8("v193",F2,H2) D8("v194",G2,H2) D8("v195",O2,H2) \
 D8("v192",I3,H3) D8("v193",F3,H3) D8("v194",G3,H3) D8("v195",O3,H3)

#define LSTM_BODY(XI, XF, XG, XO, NQUAD) \
  "ds_read_b128 v[160:163], v206\n\t" \
  "ds_read_b128 v[164:167], v206 offset:16\n\t" \
  "ds_read_b128 v[168:171], v206 offset:32\n\t" \
  "ds_read_b128 v[172:175], v206 offset:48\n\t" \
  "ds_read_b128 v[176:179], v206 offset:64\n\t" \
  "ds_read_b128 v[180:183], v206 offset:80\n\t" \
  "ds_read_b128 v[184:187], v206 offset:96\n\t" \
  "ds_read_b128 v[188:191], v206 offset:112\n\t" \
  "v_xor_b32 v206, 0x80, v206\n\t" \
  "global_store_dword v205, v218, %[shs]\n\t" \
  "v_add_u32 v205, 0x400, v205\n\t" \
  "global_load_dwordx4 " NQUAD ", v204, %[sxg]\n\t" \
  "v_add_u32 v204, 0x1000, v204\n\t" \
  "s_waitcnt lgkmcnt(7)\n\t" \
  CH("v160","v161","v162","v163", "v32","v33","v34","v35", "v64","v65","v66","v67", "v96","v97","v98","v99", "v128","v129","v130","v131") \
  "s_waitcnt lgkmcnt(6)\n\t" \
  CH("v164","v165","v166","v167", "v36","v37","v38","v39", "v68","v69","v70","v71", "v100","v101","v102","v103", "v132","v133","v134","v135") \
  "s_waitcnt lgkmcnt(5)\n\t" \
  CH("v168","v169","v170","v171", "v40","v41","v42","v43", "v72","v73","v74","v75", "v104","v105","v106","v107", "v136","v137","v138","v139") \
  "s_waitcnt lgkmcnt(4)\n\t" \
  CH("v172","v173","v174","v175", "v44","v45","v46","v47", "v76","v77","v78","v79", "v108","v109","v110","v111", "v140","v141","v142","v143") \
  "s_waitcnt lgkmcnt(3)\n\t" \
  CH("v176","v177","v178","v179", "v48","v49","v50","v51", "v80","v81","v82","v83", "v112","v113","v114","v115", "v144","v145","v146","v147") \
  "s_waitcnt lgkmcnt(2)\n\t" \
  CH("v180","v181","v182","v183", "v52","v53","v54","v55", "v84","v85","v86","v87", "v116","v117","v118","v119", "v148","v149","v150","v151") \
  "s_waitcnt lgkmcnt(1)\n\t" \
  CH("v184","v185","v186","v187", "v56","v57","v58","v59", "v88","v89","v90","v91", "v120","v121","v122","v123", "v152","v153","v154","v155") \
  "s_waitcnt lgkmcnt(0)\n\t" \
  CH("v188","v189","v190","v191", "v60","v61","v62","v63", "v92","v93","v94","v95", "v124","v125","v126","v127", "v156","v157","v158","v159") \
  "v_cvt_f32_i32 v208, v192\n\t" \
  "v_cvt_f32_i32 v209, v193\n\t" \
  "v_cvt_f32_i32 v210, v194\n\t" \
  "v_cvt_f32_i32 v211, v195\n\t" \
  "s_waitcnt vmcnt(2)\n\t" \
  "v_fma_f32 v212, %[sci], v208, " XI "\n\t" \
  "v_fma_f32 v213, %[scf], v209, " XF "\n\t" \
  "v_fma_f32 v214, %[scg], v210, " XG "\n\t" \
  "v_fma_f32 v215, %[sco], v211, " XO "\n\t" \
  "v_mul_f32 v208, %[nk], v212\n\t" \
  "v_mul_f32 v209, %[nk], v213\n\t" \
  "v_mul_f32 v211, %[nk], v215\n\t" \
  "v_med3_f32 v214, v214, %[ncl], %[pcl]\n\t" \
  "v_mul_f32 v210, %[k2], v214\n\t" \
  "v_exp_f32 v208, v208\n\t" \
  "v_exp_f32 v209, v209\n\t" \
  "v_exp_f32 v211, v211\n\t" \
  "v_exp_f32 v210, v210\n\t" \
  "s_nop 1\n\t" \
  "v_add_f32 v212, 1.0, v208\n\t" \
  "v_add_f32 v213, 1.0, v209\n\t" \
  "v_add_f32 v215, 1.0, v211\n\t" \
  "v_add_f32 v216, 1.0, v210\n\t" \
  "v_add_f32 v217, -1.0, v210\n\t" \
  "v_rcp_f32 v212, v212\n\t" \
  "v_rcp_f32 v213, v213\n\t" \
  "v_rcp_f32 v215, v215\n\t" \
  "v_rcp_f32 v216, v216\n\t" \
  "s_nop 1\n\t" \
  "v_mul_f32 v217, v217, v216\n\t" \
  "v_mul_f32 v219, %[c7], v215\n\t" \
  "v_mul_f32 v220, v213, v220\n\t" \
  "v_fmac_f32 v220, v212, v217\n\t" \
  "v_med3_f32 v208, v220, %[ncl], %[pcl]\n\t" \
  "v_mul_f32 v208, %[k2], v208\n\t" \
  "v_exp_f32 v208, v208\n\t" \
  "s_nop 1\n\t" \
  "v_add_f32 v209, -1.0, v208\n\t" \
  "v_add_f32 v210, 1.0, v208\n\t" \
  "v_rcp_f32 v210, v210\n\t" \
  "s_nop 1\n\t" \
  "v_mul_f32 v209, v209, v210\n\t" \
  "v_mul_f32 v217, v219, v209\n\t" \
  "v_add_f32 v208, 0x4b400000, v217\n\t" \
  "v_and_b32 v208, 15, v208\n\t" \
  "v_lshlrev_b32 v208, v225, v208\n\t" \
  "v_mul_f32 v218, %[i7], v217\n\t" \
  "s_nop 1\n\t" \
  "v_mov_b32_dpp v209, v208 quad_perm:[1,0,3,2] row_mask:0xf bank_mask:0xf\n\t" \
  "v_or_b32 v208, v208, v209\n\t" \
  "s_nop 1\n\t" \
  "v_mov_b32_dpp v209, v208 quad_perm:[2,3,0,1] row_mask:0xf bank_mask:0xf\n\t" \
  "v_or_b32 v208, v208, v209\n\t" \
  "ds_write_b16 v207, v208\n\t" \
  "v_xor_b32 v207, 0x80, v207\n\t" \
  "v_mov_b32 v192, 0\n\t" \
  "v_mov_b32 v193, 0\n\t" \
  "v_mov_b32 v194, 0\n\t" \
  "v_mov_b32 v195, 0\n\t" \
  "s_waitcnt lgkmcnt(0)\n\t" \
  "s_barrier\n\t"

__global__ __launch_bounds__(256, 1) void lstm_kernel(
    const float* __restrict__ xg, const int* __restrict__ wq4,
    const float* __restrict__ wscale, const int* __restrict__ hq0p,
    const float* __restrict__ c0, float* __restrict__ hs)
{
    const int d = blockIdx.x;
    const int t = threadIdx.x;   // cell index 0..255

    __shared__ alignas(16) int hq4buf[512];  // 2KB: buf0 @0, buf1 @128B, dump @512B

    const int*   wq_d = wq4 + (size_t)d * 32768;
    const float* xg_d = xg + (size_t)d * S * 1024;
    float*       hs_d = hs + (size_t)d * DSTRIDE_F;   // slack row first
    const float sci = wscale[d * 1024 + t]       * (1.0f / 7.0f);
    const float scf = wscale[d * 1024 + 256 + t] * (1.0f / 7.0f);
    const float scg = wscale[d * 1024 + 512 + t] * (1.0f / 7.0f);
    const float sco = wscale[d * 1024 + 768 + t] * (1.0f / 7.0f);
    const float c0v = c0[d * 256 + t];
    const int h0v = hq0p[d * 32 + (t & 31)];
    const unsigned h0a = (t < 32) ? (unsigned)t * 4u : (1536u + (unsigned)(t & 63) * 4u);
    const unsigned xai = (unsigned)t * 16u;
    const unsigned hsi = (unsigned)t * 4u;      // first (lagged) store -> slack row
    const unsigned wad = ((t & 3) == 0) ? (128u + (unsigned)(t >> 1))
                                        : (512u + (unsigned)((t & 255) << 2));
    const unsigned voW = (unsigned)t * 128u;   // row m base; +0x8000 per gate
    const unsigned shf = (unsigned)(t & 3) * 4u;
    const float nk = -1.4426950408889634f;
    const float k2 = 2.8853900817779268f;
    const float c7 = 7.0f;
    const float i7 = 1.0f / 7.0f;
    const float ncl = -30.0f, pcl = 30.0f;
    const unsigned lds_keep = (unsigned)(size_t)&hq4buf[0];
    int cnt = S / 2;   // body unrolled x2

    asm volatile(
        // ---- prologue ----
        "v_mov_b32 v204, %[xai]\n\t"
        "v_mov_b32 v205, %[hsi]\n\t"
        "v_mov_b32 v206, 0\n\t"
        "v_mov_b32 v207, %[wad]\n\t"
        "v_mov_b32 v218, 0\n\t"
        "v_mov_b32 v220, %[c0v]\n\t"
        "v_mov_b32 v225, %[shf]\n\t"
        "v_mov_b32 v192, 0\n\t"
        "v_mov_b32 v193, 0\n\t"
        "v_mov_b32 v194, 0\n\t"
        "v_mov_b32 v195, 0\n\t"
        "ds_write_b32 %[h0a], %[h0v]\n\t"
        "v_mov_b32 v208, %[voW]\n\t"
        "global_load_dwordx4 v[32:35], v208, %[swq]\n\t"
        "global_load_dwordx4 v[36:39], v208, %[swq] offset:16\n\t"
        "global_load_dwordx4 v[40:43], v208, %[swq] offset:32\n\t"
        "global_load_dwordx4 v[44:47], v208, %[swq] offset:48\n\t"
        "global_load_dwordx4 v[48:51], v208, %[swq] offset:64\n\t"
        "global_load_dwordx4 v[52:55], v208, %[swq] offset:80\n\t"
        "global_load_dwordx4 v[56:59], v208, %[swq] offset:96\n\t"
        "global_load_dwordx4 v[60:63], v208, %[swq] offset:112\n\t"
        "v_add_u32 v208, 0x8000, v208\n\t"
        "global_load_dwordx4 v[64:67], v208, %[swq]\n\t"
        "global_load_dwordx4 v[68:71], v208, %[swq] offset:16\n\t"
        "global_load_dwordx4 v[72:75], v208, %[swq] offset:32\n\t"
        "global_load_dwordx4 v[76:79], v208, %[swq] offset:48\n\t"
        "global_load_dwordx4 v[80:83], v208, %[swq] offset:64\n\t"
        "global_load_dwordx4 v[84:87], v208, %[swq] offset:80\n\t"
        "global_load_dwordx4 v[88:91], v208, %[swq] offset:96\n\t"
        "global_load_dwordx4 v[92:95], v208, %[swq] offset:112\n\t"
        "v_add_u32 v208, 0x8000, v208\n\t"
        "global_load_dwordx4 v[96:99],   v208, %[swq]\n\t"
        "global_load_dwordx4 v[100:103], v208, %[swq] offset:16\n\t"
        "global_load_dwordx4 v[104:107], v208, %[swq] offset:32\n\t"
        "global_load_dwordx4 v[108:111], v208, %[swq] offset:48\n\t"
        "global_load_dwordx4 v[112:115], v208, %[swq] offset:64\n\t"
        "global_load_dwordx4 v[116:119], v208, %[swq] offset:80\n\t"
        "global_load_dwordx4 v[120:123], v208, %[swq] offset:96\n\t"
        "global_load_dwordx4 v[124:127], v208, %[swq] offset:112\n\t"
        "v_add_u32 v208, 0x8000, v208\n\t"
        "global_load_dwordx4 v[128:131], v208, %[swq]\n\t"
        "global_load_dwordx4 v[132:135], v208, %[swq] offset:16\n\t"
        "global_load_dwordx4 v[136:139], v208, %[swq] offset:32\n\t"
        "global_load_dwordx4 v[140:143], v208, %[swq] offset:48\n\t"
        "global_load_dwordx4 v[144:147], v208, %[swq] offset:64\n\t"
        "global_load_dwordx4 v[148:151], v208, %[swq] offset:80\n\t"
        "global_load_dwordx4 v[152:155], v208, %[swq] offset:96\n\t"
        "global_load_dwordx4 v[156:159], v208, %[swq] offset:112\n\t"
        "global_load_dwordx4 v[196:199], v204, %[sxg]\n\t"
        "v_add_u32 v204, 0x1000, v204\n\t"
        "s_waitcnt vmcnt(0) lgkmcnt(0)\n\t"
        "s_barrier\n\t"
        // ---- main loop: 2 steps per iteration (depth-1 xg rotation) ----
        "Llstm%=:\n\t"
        LSTM_BODY("v196", "v197", "v198", "v199", "v[200:203]")
        LSTM_BODY("v200", "v201", "v202", "v203", "v[196:199]")
        "s_add_i32 %[cnt], %[cnt], -1\n\t"
        "s_cmp_lg_u32 %[cnt], 0\n\t"
        "s_cbranch_scc1 Llstm%=\n\t"
        // ---- epilogue: store last h ----
        "global_store_dword v205, v218, %[shs]\n\t"
        : [cnt] "+s"(cnt)
        : [sxg] "s"(xg_d), [shs] "s"(hs_d), [swq] "s"(wq_d),
          [xai] "v"(xai), [hsi] "v"(hsi), [wad] "v"(wad),
          [c0v] "v"(c0v), [h0a] "v"(h0a), [h0v] "v"(h0v),
          [sci] "v"(sci), [scf] "v"(scf), [scg] "v"(scg), [sco] "v"(sco),
          [nk] "v"(nk), [k2] "v"(k2), [c7] "v"(c7), [i7] "v"(i7),
          [ncl] "v"(ncl), [pcl] "v"(pcl),
          [voW] "v"(voW), [shf] "v"(shf), [keep] "v"(lds_keep)
        : "memory", "scc",
          "v32","v33","v34","v35","v36","v37","v38","v39",
          "v40","v41","v42","v43","v44","v45","v46","v47",
          "v48","v49","v50","v51","v52","v53","v54","v55",
          "v56","v57","v58","v59","v60","v61","v62","v63",
          "v64","v65","v66","v67","v68","v69","v70","v71",
          "v72","v73","v74","v75","v76","v77","v78","v79",
          "v80","v81","v82","v83","v84","v85","v86","v87",
          "v88","v89","v90","v91","v92","v93","v94","v95",
          "v96","v97","v98","v99","v100","v101","v102","v103",
          "v104","v105","v106","v107","v108","v109","v110","v111",
          "v112","v113","v114","v115","v116","v117","v118","v119",
          "v120","v121","v122","v123","v124","v125","v126","v127",
          "v128","v129","v130","v131","v132","v133","v134","v135",
          "v136","v137","v138","v139","v140","v141","v142","v143",
          "v144","v145","v146","v147","v148","v149","v150","v151",
          "v152","v153","v154","v155","v156","v157","v158","v159",
          "v160","v161","v162","v163","v164","v165","v166","v167",
          "v168","v169","v170","v171","v172","v173","v174","v175",
          "v176","v177","v178","v179","v180","v181","v182","v183",
          "v184","v185","v186","v187","v188","v189","v190","v191",
          "v192","v193","v194","v195","v196","v197","v198","v199",
          "v200","v201","v202","v203","v204","v205","v206","v207",
          "v208","v209","v210","v211","v212","v213","v214","v215",
          "v216","v217","v218","v219","v220","v221","v222","v223",
          "v224","v225");
}

// ---------- K3: feats[t][tag] = b_out[tag] + W_out[tag] . [hf[t], hb[t]] ----------
__global__ __launch_bounds__(256) void feats_kernel(
    const float* __restrict__ hsf, const float* __restrict__ hsb,
    const float* __restrict__ Wout,
    const float* __restrict__ bout, float* __restrict__ feats)
{
    __shared__ float Wl[16][513];
    int tid = threadIdx.x;
    for (int i = tid; i < 16 * 512; i += 256) Wl[i >> 9][i & 511] = Wout[i];
    __syncthreads();
    int tt = tid >> 4, tag = tid & 15;
    int tcur = blockIdx.x * 16 + tt;
    const float* hf = hsf + (size_t)tcur * 256;
    const float* hb = hsb + (size_t)(S - 1 - tcur) * 256;
    float acc = bout[tag];
    for (int k = 0; k < 256; ++k) acc += Wl[tag][k] * hf[k];
    for (int k = 0; k < 256; ++k) acc += Wl[tag][256 + k] * hb[k];
    feats[(size_t)tcur * 16 + tag] = acc;
}

// ---------- K4a: CRF chunk products in log semiring ----------
__global__ __launch_bounds__(256) void crf_chunk_kernel(
    const float* __restrict__ feats, const float* __restrict__ trans,
    float* __restrict__ P)
{
    int chunk = blockIdx.x;
    int tid = threadIdx.x;
    int i = tid >> 4, jj = tid & 15;
    __shared__ float Mt[2][16][17];   // Mt[buf][j][k] = M[k][j]
    float tr[16];
    #pragma unroll
    for (int k = 0; k < 16; ++k) tr[k] = trans[i * 16 + k];
    int t0 = chunk * 64;
    float emit = feats[(size_t)t0 * 16 + i];
    Mt[0][jj][i] = tr[jj] + emit;     // init M = A_{t0}
    __syncthreads();
    int cur = 0;
    float em_next = feats[(size_t)(t0 + 1) * 16 + i];
    for (int s = 1; s < 64; ++s) {
        float em = em_next;
        if (s + 1 < 64) em_next = feats[(size_t)(t0 + s + 1) * 16 + i];
        float v[16];
        #pragma unroll
        for (int k = 0; k < 16; ++k) v[k] = tr[k] + Mt[cur][jj][k];
        float m = v[0];
        #pragma unroll
        for (int k = 1; k < 16; ++k) m = fmaxf(m, v[k]);
        float ssum = 0.f;
        #pragma unroll
        for (int k = 0; k < 16; ++k) ssum += fast_exp(v[k] - m);
        float nv = em + m + fast_log(ssum);
        Mt[cur ^ 1][jj][i] = nv;
        cur ^= 1;
        __syncthreads();
    }
    P[((size_t)chunk * 16 + i) * 16 + jj] = Mt[cur][jj][i];
}

// ---------- K4b: fold 64 chunk matrices through alpha ----------
__global__ __launch_bounds__(256) void crf_fold_kernel(
    const float* __restrict__ P, const float* __restrict__ trans,
    float* __restrict__ out)
{
    int tid = threadIdx.x;
    int i = tid >> 4, jj = tid & 15;
    __shared__ float alpha[16];
    if (tid < 16) alpha[tid] = (tid == START_) ? 0.0f : NEG_;
    __syncthreads();
    for (int cc = 0; cc < 64; ++cc) {
        float pv = P[((size_t)cc * 16 + i) * 16 + jj];
        float v = pv + alpha[jj];
        float m = v;
        #pragma unroll
        for (int off = 1; off < 16; off <<= 1) m = fmaxf(m, __shfl_xor(m, off, 64));
        float e = fast_exp(v - m);
        #pragma unroll
        for (int off = 1; off < 16; off <<= 1) e += __shfl_xor(e, off, 64);
        float nv = m + fast_log(e);
        __syncthreads();
        if (jj == 0) alpha[i] = nv;
        __syncthreads();
    }
    if (tid < 16) {
        float v = alpha[tid] + trans[STOP_ * 16 + tid];
        float m = v;
        #pragma unroll
        for (int off = 1; off < 16; off <<= 1) m = fmaxf(m, __shfl_xor(m, off, 64));
        float e = fast_exp(v - m);
        #pragma unroll
        for (int off = 1; off < 16; off <<= 1) e += __shfl_xor(e, off, 64);
        if (tid == 0) out[0] = m + fast_log(e);
    }
}

extern "C" void kernel_launch(void* const* d_in, const int* in_sizes, int n_in,
                              void* d_out, int out_size, void* d_ws, size_t ws_size,
                              hipStream_t stream) {
    const int*   sent  = (const int*)d_in[0];
    const float* embed = (const float*)d_in[1];
    const float* Wihf  = (const float*)d_in[2];
    const float* Whhf  = (const float*)d_in[3];
    const float* bihf  = (const float*)d_in[4];
    const float* bhhf  = (const float*)d_in[5];
    const float* Wihb  = (const float*)d_in[6];
    const float* Whhb  = (const float*)d_in[7];
    const float* bihb  = (const float*)d_in[8];
    const float* bhhb  = (const float*)d_in[9];
    const float* Wout  = (const float*)d_in[10];
    const float* bout  = (const float*)d_in[11];
    const float* trans = (const float*)d_in[12];
    const float* h0    = (const float*)d_in[13];
    const float* c0    = (const float*)d_in[14];
    float* out = (float*)d_out;

    char* ws = (char*)d_ws;
    constexpr size_t OFF_XG     = 0;                                      // 32MB
    constexpr size_t OFF_WQ     = OFF_XG + (size_t)2 * S * 1024 * 4;      // 256KB (int4)
    constexpr size_t OFF_WSCALE = OFF_WQ + (size_t)2 * 1024 * 32 * 4;     // 8KB
    constexpr size_t OFF_HQ0    = OFF_WSCALE + 2 * 1024 * 4;              // 256B
    constexpr size_t OFF_WT     = OFF_HQ0 + 256;                          // 2MB
    constexpr size_t OFF_HS     = OFF_WT + (size_t)2 * 256 * 1024 * 4;    // 2*(4MB+1KB)
    constexpr size_t OFF_FEATS  = OFF_HS + (size_t)2 * DSTRIDE_F * 4;     // 256KB
    constexpr size_t OFF_P      = OFF_FEATS + (size_t)S * 16 * 4;         // 64KB

    float* xg     = (float*)(ws + OFF_XG);
    int*   wq4    = (int*)(ws + OFF_WQ);
    float* wscale = (float*)(ws + OFF_WSCALE);
    int*   hq0p   = (int*)(ws + OFF_HQ0);
    float* WT     = (float*)(ws + OFF_WT);
    float* hs     = (float*)(ws + OFF_HS);
    float* feats  = (float*)(ws + OFF_FEATS);
    float* P      = (float*)(ws + OFF_P);

    quant4_kernel<<<dim3(2050), dim3(64), 0, stream>>>(Whhf, Whhb, h0, wq4, wscale, hq0p);
    transpose_kernel<<<dim3(32, 8, 2), dim3(256), 0, stream>>>(Wihf, Wihb, WT);
    xg_kernel<<<dim3(256, 2), dim3(256), 0, stream>>>(sent, embed, WT, bihf, bhhf,
                                                      bihb, bhhb, xg);
    lstm_kernel<<<dim3(2), dim3(256), 0, stream>>>(xg, wq4, wscale, hq0p, c0, hs);
    feats_kernel<<<dim3(256), dim3(256), 0, stream>>>(hs + 256, hs + DSTRIDE_F + 256,
                                                      Wout, bout, feats);
    crf_chunk_kernel<<<dim3(64), dim3(256), 0, stream>>>(feats, trans, P);
    crf_fold_kernel<<<dim3(1), dim3(256), 0, stream>>>(P, trans, out);
}